// Round 4
// baseline (1024.893 us; speedup 1.0000x reference)
//
#include <hip/hip_runtime.h>
#include <hip/hip_cooperative_groups.h>

namespace cg = cooperative_groups;

#define N_NODES 10000
#define N_EDGES 320000
#define E_TOT   (N_EDGES + N_NODES)
#define HID 256
#define NEG_SLOPE 0.2f
#define SLOTS 192   // fixed CSR slots/node; deg ~ Binom(320k,1e-4), mean 32
#define RGROUPS (N_NODES / 16)   // 625 16-row GEMM groups (exact)

typedef __attribute__((ext_vector_type(8))) short short8;
typedef __attribute__((ext_vector_type(4))) float float4v;

// ---- all scratch in module-scope device globals (no d_ws dependency) ----
__device__ int   g_cnt[N_NODES];
__device__ int   g_csr[(size_t)N_NODES * SLOTS];
__device__ __align__(16) float g_xl[(size_t)N_NODES * HID];
__device__ __align__(16) float g_xr[(size_t)N_NODES * HID];
__device__ __align__(16) float g_h1[(size_t)N_NODES * HID];
__device__ __align__(16) unsigned short g_xlb[(size_t)N_NODES * HID];
__device__ __align__(16) unsigned short g_abf[(size_t)N_NODES * 512];
__device__ __align__(16) unsigned short g_bp1a[16 * 8  * 64 * 8];  // W1l
__device__ __align__(16) unsigned short g_bp2a[16 * 8  * 64 * 8];  // W1r
__device__ __align__(16) unsigned short g_bp1b[16 * 16 * 64 * 8];  // W2l
__device__ __align__(16) unsigned short g_bp2b[16 * 16 * 64 * 8];  // W2r
__device__ __align__(16) unsigned short g_bp1c[2  * 16 * 64 * 8];  // W3l
__device__ __align__(16) unsigned short g_bp2c[2  * 16 * 64 * 8];  // W3r

#define LOG2E 1.44269504088896340736f

// ---------------- bf16 helpers (RNE) ----------------
__device__ __forceinline__ unsigned short f2bf(float f) {
    unsigned int u = __float_as_uint(f);
    unsigned int r = (u + 0x7fffu + ((u >> 16) & 1u)) >> 16;
    return (unsigned short)r;
}
__device__ __forceinline__ float bf2f(unsigned short h) {
    return __uint_as_float(((unsigned int)h) << 16);
}
__device__ __forceinline__ unsigned int splitpack(float f) {
    unsigned short hi = f2bf(f);
    unsigned short lo = f2bf(f - bf2f(hi));
    return ((unsigned int)lo << 16) | hi;   // mem halfwords: [2i]=hi, [2i+1]=lo
}

// pack one weight matrix B[K,N] into per-lane MFMA B-fragments (split-bf16).
__device__ __forceinline__ void packB(const float* __restrict__ B,
                                      unsigned short* __restrict__ Bp,
                                      int t, int nkc, int N) {
    int lane = t & 63;
    int kc   = (t >> 6) % nkc;
    int nt   = (t >> 6) / nkc;
    int n = nt * 16 + (lane & 15);
    int kbase = kc * 32 + (lane >> 4) * 8;
    #pragma unroll
    for (int j = 0; j < 8; ++j) {
        int kp = kbase + j;
        int k  = kp >> 1;
        float f = B[(size_t)k * N + n];
        unsigned short hi = f2bf(f);
        Bp[(size_t)t * 8 + j] = (kp & 1) ? f2bf(f - bf2f(hi)) : hi;
    }
}

// =================== mega-kernel phase device functions ===================

// layer-1 GEMM, one 16-row group: A = x (f32, inline split), dual B (W1l/W1r)
__device__ __forceinline__ void gemm1_tile(int rg, int lane, int wid,
                                           const float4* __restrict__ A4) {
    int quad = lane >> 4, col = lane & 15;
    int arow = rg * 16 + col;
    const float4* a0 = A4 + (size_t)arow * 32;   // 128 f32 = 32 float4
    const short8* Bp1 = (const short8*)g_bp1a;
    const short8* Bp2 = (const short8*)g_bp2a;
    float4v acc[4][2];
    #pragma unroll
    for (int t = 0; t < 4; ++t) { acc[t][0] = (float4v)(0.f); acc[t][1] = (float4v)(0.f); }
    for (int kc = 0; kc < 8; ++kc) {
        float4 v0 = a0[kc * 4 + quad];
        union { short8 s; unsigned int u[4]; } c0;
        c0.u[0] = splitpack(v0.x); c0.u[1] = splitpack(v0.y);
        c0.u[2] = splitpack(v0.z); c0.u[3] = splitpack(v0.w);
        short8 A0 = c0.s;
        #pragma unroll
        for (int t = 0; t < 4; ++t) {
            int nt = wid * 4 + t;
            size_t bi = ((size_t)(nt * 8 + kc)) * 64 + lane;
            acc[t][0] = __builtin_amdgcn_mfma_f32_16x16x32_bf16(A0, Bp1[bi], acc[t][0], 0, 0, 0);
            acc[t][1] = __builtin_amdgcn_mfma_f32_16x16x32_bf16(A0, Bp2[bi], acc[t][1], 0, 0, 0);
        }
    }
    #pragma unroll
    for (int t = 0; t < 4; ++t) {
        int gc = (wid * 4 + t) * 16 + col;
        #pragma unroll
        for (int r = 0; r < 4; ++r) {
            int row = rg * 16 + quad * 4 + r;
            g_xlb[(size_t)row * 256 + gc] = f2bf(acc[t][0][r]);
            g_xr [(size_t)row * 256 + gc] = acc[t][1][r];
        }
    }
}

// layer-2 GEMM, one 16-row group: A = abf (pre-split, Kp=512), dual B (W2l/W2r)
__device__ __forceinline__ void gemm2_tile(int rg, int lane, int wid) {
    int quad = lane >> 4, col = lane & 15;
    int arow = rg * 16 + col;
    const short8* a0 = (const short8*)g_abf + (size_t)arow * 64;  // Kp/8 = 64
    const short8* Bp1 = (const short8*)g_bp1b;
    const short8* Bp2 = (const short8*)g_bp2b;
    float4v acc[4][2];
    #pragma unroll
    for (int t = 0; t < 4; ++t) { acc[t][0] = (float4v)(0.f); acc[t][1] = (float4v)(0.f); }
    for (int kc = 0; kc < 16; ++kc) {
        short8 A0 = a0[kc * 4 + quad];
        #pragma unroll
        for (int t = 0; t < 4; ++t) {
            int nt = wid * 4 + t;
            size_t bi = ((size_t)(nt * 16 + kc)) * 64 + lane;
            acc[t][0] = __builtin_amdgcn_mfma_f32_16x16x32_bf16(A0, Bp1[bi], acc[t][0], 0, 0, 0);
            acc[t][1] = __builtin_amdgcn_mfma_f32_16x16x32_bf16(A0, Bp2[bi], acc[t][1], 0, 0, 0);
        }
    }
    #pragma unroll
    for (int t = 0; t < 4; ++t) {
        int gc = (wid * 4 + t) * 16 + col;
        #pragma unroll
        for (int r = 0; r < 4; ++r) {
            int row = rg * 16 + quad * 4 + r;
            g_xlb[(size_t)row * 256 + gc] = f2bf(acc[t][0][r]);
            g_xr [(size_t)row * 256 + gc] = acc[t][1][r];
        }
    }
}

// layer-3 GEMM, one 16-row group: N=32 per matrix, Kp=512, f32 outputs
__device__ __forceinline__ void gemm3_tile(int rg, int lane, int wid) {
    int quad = lane >> 4, col = lane & 15;
    int nt   = wid & 1;
    const short8* Bp = (wid < 2) ? (const short8*)g_bp1c : (const short8*)g_bp2c;
    float* C = (wid < 2) ? g_xl : g_xr;
    const short8* abase = (const short8*)g_abf + (size_t)(rg * 16 + col) * 64 + quad;
    float4v acc = (float4v)(0.f);
    #pragma unroll 4
    for (int kc = 0; kc < 16; ++kc) {
        short8 a = abase[kc * 4];
        short8 b = Bp[((size_t)(nt * 16 + kc)) * 64 + lane];
        acc = __builtin_amdgcn_mfma_f32_16x16x32_bf16(a, b, acc, 0, 0, 0);
    }
    #pragma unroll
    for (int r = 0; r < 4; ++r)
        C[(size_t)(rg * 16 + quad * 4 + r) * 32 + nt * 16 + col] = acc[r];
}

// GATv2 aggregation, heads=8, one node per wave (8 edges in flight)
template<int MODE>
__device__ __forceinline__ void agg8_node(int node, int lane,
                                          const float4* __restrict__ att4,
                                          const float4* __restrict__ bias4) {
    const unsigned short* xlb = g_xlb;
    const float4* xr4 = (const float4*)g_xr;
    float4 xrv = xr4[(size_t)node * 64 + lane];
    float4 av  = att4[lane];
    av.x *= LOG2E; av.y *= LOG2E; av.z *= LOG2E; av.w *= LOG2E;
    int c = g_cnt[node]; if (c > SLOTS) c = SLOTS;
    int base0 = node * SLOTS;

    float s = 0.f;
    float4 acc = make_float4(0.f, 0.f, 0.f, 0.f);

    for (int base = 0; base < c; base += 64) {
        int li = base + lane;
        int idxv = g_csr[base0 + (li < c ? li : c - 1)];
        int m = c - base; if (m > 64) m = 64;
        for (int j0 = 0; j0 < m; j0 += 8) {
            int srcs[8];
            ushort4 uv[8];
            #pragma unroll
            for (int j = 0; j < 8; ++j)
                srcs[j] = __shfl(idxv, j0 + j);
            #pragma unroll
            for (int j = 0; j < 8; ++j)
                uv[j] = *(const ushort4*)(xlb + (size_t)srcs[j] * 256 + 4 * lane);
            #pragma unroll
            for (int j = 0; j < 8; ++j) {
                if (j0 + j < m) {
                    float4 xv;
                    xv.x = bf2f(uv[j].x); xv.y = bf2f(uv[j].y);
                    xv.z = bf2f(uv[j].z); xv.w = bf2f(uv[j].w);
                    float tx = xv.x + xrv.x, ty = xv.y + xrv.y;
                    float tz = xv.z + xrv.z, tw = xv.w + xrv.w;
                    float w = fmaxf(tx, NEG_SLOPE * tx) * av.x
                            + fmaxf(ty, NEG_SLOPE * ty) * av.y
                            + fmaxf(tz, NEG_SLOPE * tz) * av.z
                            + fmaxf(tw, NEG_SLOPE * tw) * av.w;
                    w += __shfl_xor(w, 1);
                    w += __shfl_xor(w, 2);
                    w += __shfl_xor(w, 4);
                    float p = exp2f(w);
                    s += p;
                    acc.x += p * xv.x;
                    acc.y += p * xv.y;
                    acc.z += p * xv.z;
                    acc.w += p * xv.w;
                }
            }
        }
    }

    float inv = 1.f / (s + 1e-16f);
    float4 bv = bias4[lane];
    float4 o;
    o.x = acc.x * inv + bv.x; o.y = acc.y * inv + bv.y;
    o.z = acc.z * inv + bv.z; o.w = acc.w * inv + bv.w;
    if (MODE == 0) {
        o.x = fmaxf(o.x, 0.f); o.y = fmaxf(o.y, 0.f);
        o.z = fmaxf(o.z, 0.f); o.w = fmaxf(o.w, 0.f);
        ((float4*)g_h1)[(size_t)node * 64 + lane] = o;
    } else {
        float4 r = ((const float4*)g_h1)[(size_t)node * 64 + lane];
        o.x += r.x; o.y += r.y; o.z += r.z; o.w += r.w;
    }
    uint4 u;
    u.x = splitpack(o.x); u.y = splitpack(o.y);
    u.z = splitpack(o.z); u.w = splitpack(o.w);
    ((uint4*)g_abf)[(size_t)node * 64 + lane] = u;
}

// GATv2 aggregation, heads=1, one node per wave (8 lane-groups, 2-deep)
__device__ __forceinline__ void agg1_node(int node, int lane,
                                          const float4* __restrict__ att4,
                                          const float4* __restrict__ bias4,
                                          float4* __restrict__ out4) {
    const float4* xl4 = (const float4*)g_xl;
    const float4* xr4 = (const float4*)g_xr;
    int q = lane & 7;
    int grp = lane >> 3;
    float4 xrv = xr4[(size_t)node * 8 + q];
    float4 av  = att4[q];
    av.x *= LOG2E; av.y *= LOG2E; av.z *= LOG2E; av.w *= LOG2E;
    int c = g_cnt[node]; if (c > SLOTS) c = SLOTS;
    int start = node * SLOTS, end = start + c;
    float s = 0.f;
    float4 acc = make_float4(0.f, 0.f, 0.f, 0.f);
    for (int i = start + grp; i < end; i += 16) {
        int i2 = i + 8;
        bool has2 = i2 < end;
        int src0 = g_csr[i];
        int src1 = g_csr[has2 ? i2 : i];
        float4 xv0 = xl4[(size_t)src0 * 8 + q];
        float4 xv1 = xl4[(size_t)src1 * 8 + q];
        {
            float tx = xv0.x + xrv.x, ty = xv0.y + xrv.y;
            float tz = xv0.z + xrv.z, tw = xv0.w + xrv.w;
            float w = fmaxf(tx, NEG_SLOPE * tx) * av.x
                    + fmaxf(ty, NEG_SLOPE * ty) * av.y
                    + fmaxf(tz, NEG_SLOPE * tz) * av.z
                    + fmaxf(tw, NEG_SLOPE * tw) * av.w;
            w += __shfl_xor(w, 1);
            w += __shfl_xor(w, 2);
            w += __shfl_xor(w, 4);
            float p = exp2f(w);
            s += p;
            acc.x += p * xv0.x; acc.y += p * xv0.y;
            acc.z += p * xv0.z; acc.w += p * xv0.w;
        }
        if (has2) {
            float tx = xv1.x + xrv.x, ty = xv1.y + xrv.y;
            float tz = xv1.z + xrv.z, tw = xv1.w + xrv.w;
            float w = fmaxf(tx, NEG_SLOPE * tx) * av.x
                    + fmaxf(ty, NEG_SLOPE * ty) * av.y
                    + fmaxf(tz, NEG_SLOPE * tz) * av.z
                    + fmaxf(tw, NEG_SLOPE * tw) * av.w;
            w += __shfl_xor(w, 1);
            w += __shfl_xor(w, 2);
            w += __shfl_xor(w, 4);
            float p = exp2f(w);
            s += p;
            acc.x += p * xv1.x; acc.y += p * xv1.y;
            acc.z += p * xv1.z; acc.w += p * xv1.w;
        }
    }
    #pragma unroll
    for (int off = 8; off < 64; off <<= 1) {
        s     += __shfl_xor(s, off);
        acc.x += __shfl_xor(acc.x, off);
        acc.y += __shfl_xor(acc.y, off);
        acc.z += __shfl_xor(acc.z, off);
        acc.w += __shfl_xor(acc.w, off);
    }
    if (grp == 0) {
        float inv = 1.f / (s + 1e-16f);
        float4 bv = bias4[q];
        float4 o;
        o.x = acc.x * inv + bv.x; o.y = acc.y * inv + bv.y;
        o.z = acc.z * inv + bv.z; o.w = acc.w * inv + bv.w;
        out4[(size_t)node * 8 + q] = o;
    }
}

// =================== the cooperative mega-kernel =========================
// 7 serial phases, one launch, grid.sync() between phases. All phases are
// grid-stride; per-element math is bitwise identical to the 7-kernel path.
__global__ __launch_bounds__(256, 4) void k_mega(
    const float4* __restrict__ x4,
    const float* __restrict__ W1l, const float* __restrict__ W1r,
    const float4* __restrict__ a1, const float4* __restrict__ b1,
    const float* __restrict__ W2l, const float* __restrict__ W2r,
    const float4* __restrict__ a2, const float4* __restrict__ b2,
    const float* __restrict__ W3l, const float* __restrict__ W3r,
    const float4* __restrict__ a3, const float4* __restrict__ b3,
    const int* __restrict__ ei, float4* __restrict__ out)
{
    cg::grid_group gg = cg::this_grid();
    int tid  = blockIdx.x * 256 + threadIdx.x;
    int lane = threadIdx.x & 63;
    int wid  = threadIdx.x >> 6;
    int nthr = gridDim.x * 256;
    int nwav = gridDim.x * 4;

    // P0: pack all six weight matrices + zero slot counters
    {
        const int S0 = 8192, S1 = 16384, S2 = 2048;
        for (int u = tid; u < S0 + S1 + S2 + N_NODES; u += nthr) {
            if (u < S0) {
                packB(W1l, g_bp1a, u, 8, 256);
                packB(W1r, g_bp2a, u, 8, 256);
            } else if (u < S0 + S1) {
                int v = u - S0;
                packB(W2l, g_bp1b, v, 16, 256);
                packB(W2r, g_bp2b, v, 16, 256);
            } else if (u < S0 + S1 + S2) {
                int v = u - S0 - S1;
                packB(W3l, g_bp1c, v, 16, 32);
                packB(W3r, g_bp2c, v, 16, 32);
            } else {
                g_cnt[u - S0 - S1 - S2] = 0;
            }
        }
    }
    __threadfence();
    gg.sync();

    // P1: CSR slot-fill + layer-1 dual GEMM (independent outputs)
    for (int e = tid; e < E_TOT; e += nthr) {
        int src, dst;
        if (e < N_EDGES) { src = ei[e]; dst = ei[N_EDGES + e]; }
        else             { src = dst = e - N_EDGES; }
        int pos = atomicAdd(&g_cnt[dst], 1);
        if (pos < SLOTS) g_csr[dst * SLOTS + pos] = src;
    }
    for (int rg = blockIdx.x; rg < RGROUPS; rg += gridDim.x)
        gemm1_tile(rg, lane, wid, x4);
    __threadfence();
    gg.sync();

    // P2: layer-1 aggregation (writes h1 + abf)
    for (int node = blockIdx.x * 4 + wid; node < N_NODES; node += nwav)
        agg8_node<0>(node, lane, a1, b1);
    __threadfence();
    gg.sync();

    // P3: layer-2 dual GEMM (abf -> xlb bf16 + xr f32)
    for (int rg = blockIdx.x; rg < RGROUPS; rg += gridDim.x)
        gemm2_tile(rg, lane, wid);
    __threadfence();
    gg.sync();

    // P4: layer-2 aggregation (+residual h1; writes abf)
    for (int node = blockIdx.x * 4 + wid; node < N_NODES; node += nwav)
        agg8_node<1>(node, lane, a2, b2);
    __threadfence();
    gg.sync();

    // P5: layer-3 dual GEMM (abf -> xl/xr f32 [N,32])
    for (int rg = blockIdx.x; rg < RGROUPS; rg += gridDim.x)
        gemm3_tile(rg, lane, wid);
    __threadfence();
    gg.sync();

    // P6: heads=1 aggregation -> output
    for (int node = blockIdx.x * 4 + wid; node < N_NODES; node += nwav)
        agg1_node(node, lane, a3, b3, out);
}

// ==================== legacy 7-kernel fallback path ======================

__global__ __launch_bounds__(256) void k_prep(const float* __restrict__ W1l,
                                              const float* __restrict__ W1r,
                                              int* __restrict__ cnt) {
    const int S0 = 16 * 8 * 64;
    int t = blockIdx.x * blockDim.x + threadIdx.x;
    if (t < S0) {
        packB(W1l, g_bp1a, t, 8, 256);
        packB(W1r, g_bp2a, t, 8, 256);
    } else {
        int u = t - S0;
        if (u < N_NODES) cnt[u] = 0;
    }
}

#define FILL_BLOCKS  ((E_TOT + 255) / 256)
#define PACK2_BLOCKS ((16 * 16 * 64 + 2 * 16 * 64 + 255) / 256)
__global__ __launch_bounds__(256) void k_fill_gemm1(
    const int* __restrict__ ei,
    int* __restrict__ cnt, int* __restrict__ csr,
    const float4* __restrict__ A4,
    const float* __restrict__ W2l, const float* __restrict__ W2r,
    const float* __restrict__ W3l, const float* __restrict__ W3r)
{
    if (blockIdx.x < FILL_BLOCKS) {
        int e = blockIdx.x * 256 + threadIdx.x;
        if (e < E_TOT) {
            int src, dst;
            if (e < N_EDGES) { src = ei[e]; dst = ei[N_EDGES + e]; }
            else             { src = dst = e - N_EDGES; }
            int pos = atomicAdd(&cnt[dst], 1);
            if (pos < SLOTS) csr[dst * SLOTS + pos] = src;
        }
        return;
    }
    if (blockIdx.x >= FILL_BLOCKS + RGROUPS) {
        const int S1 = 16 * 16 * 64, S2 = 2 * 16 * 64;
        int t = (blockIdx.x - FILL_BLOCKS - RGROUPS) * 256 + threadIdx.x;
        if (t < S1) {
            packB(W2l, g_bp1b, t, 16, 256);
            packB(W2r, g_bp2b, t, 16, 256);
        } else {
            int u = t - S1;
            if (u < S2) {
                packB(W3l, g_bp1c, u, 16, 32);
                packB(W3r, g_bp2c, u, 16, 32);
            }
        }
        return;
    }
    gemm1_tile(blockIdx.x - FILL_BLOCKS, threadIdx.x & 63, threadIdx.x >> 6, A4);
}

__global__ __launch_bounds__(256) void k_mgemm2_l() {
    gemm2_tile(blockIdx.x, threadIdx.x & 63, threadIdx.x >> 6);
}
__global__ __launch_bounds__(256) void k_mgemm3_l() {
    gemm3_tile(blockIdx.x, threadIdx.x & 63, threadIdx.x >> 6);
}
__global__ __launch_bounds__(256) void k_agg8_l1(const float4* __restrict__ att4,
                                                 const float4* __restrict__ bias4) {
    int node = blockIdx.x * 4 + (threadIdx.x >> 6);
    if (node >= N_NODES) return;
    agg8_node<0>(node, threadIdx.x & 63, att4, bias4);
}
__global__ __launch_bounds__(256) void k_agg8_l2(const float4* __restrict__ att4,
                                                 const float4* __restrict__ bias4) {
    int node = blockIdx.x * 4 + (threadIdx.x >> 6);
    if (node >= N_NODES) return;
    agg8_node<1>(node, threadIdx.x & 63, att4, bias4);
}
__global__ __launch_bounds__(256) void k_agg1_l(const float4* __restrict__ att4,
                                                const float4* __restrict__ bias4,
                                                float4* __restrict__ out4) {
    int node = blockIdx.x * 4 + (threadIdx.x >> 6);
    if (node >= N_NODES) return;
    agg1_node(node, threadIdx.x & 63, att4, bias4, out4);
}

// -------------------------------- launch --------------------------------

extern "C" void kernel_launch(void* const* d_in, const int* in_sizes, int n_in,
                              void* d_out, int out_size, void* d_ws, size_t ws_size,
                              hipStream_t stream) {
    const float4* x4 = (const float4*)d_in[0];
    const float* W1l = (const float*)d_in[1];
    const float* W1r = (const float*)d_in[2];
    const float4* a1 = (const float4*)d_in[3];
    const float4* b1 = (const float4*)d_in[4];
    const float* W2l = (const float*)d_in[5];
    const float* W2r = (const float*)d_in[6];
    const float4* a2 = (const float4*)d_in[7];
    const float4* b2 = (const float4*)d_in[8];
    const float* W3l = (const float*)d_in[9];
    const float* W3r = (const float*)d_in[10];
    const float4* a3 = (const float4*)d_in[11];
    const float4* b3 = (const float4*)d_in[12];
    const int*   ei  = (const int*)d_in[13];   // int32! harness converts int64 -> int32
    float4* out = (float4*)d_out;

    // decide once: cooperative mega-kernel vs legacy 7-kernel chain
    static int s_mode = -1;
    static int s_grid = 512;
    if (s_mode < 0) {
        int dev = 0;
        hipGetDevice(&dev);
        hipDeviceProp_t prop;
        hipError_t e1 = hipGetDeviceProperties(&prop, dev);
        int bpc = 0;
        hipError_t e2 = hipOccupancyMaxActiveBlocksPerMultiprocessor(
            &bpc, (const void*)k_mega, 256, 0);
        if (e1 == hipSuccess && e2 == hipSuccess && prop.cooperativeLaunch && bpc > 0) {
            long cap = (long)bpc * prop.multiProcessorCount;
            if (cap > 2048) cap = 2048;
            s_grid = (int)cap;
            s_mode = 1;
        } else {
            s_mode = 0;
        }
    }

    if (s_mode == 1) {
        void* args[] = { (void*)&x4, (void*)&W1l, (void*)&W1r, (void*)&a1, (void*)&b1,
                         (void*)&W2l, (void*)&W2r, (void*)&a2, (void*)&b2,
                         (void*)&W3l, (void*)&W3r, (void*)&a3, (void*)&b3,
                         (void*)&ei, (void*)&out };
        hipError_t err = hipLaunchCooperativeKernel((const void*)k_mega,
                                                    dim3(s_grid), dim3(256),
                                                    args, 0, stream);
        if (err == hipSuccess) return;
        s_mode = 0;   // fall through to legacy path
    }

    // ---- legacy 7-kernel path ----
    int* cnt; int* csr;
    hipGetSymbolAddress((void**)&cnt, HIP_SYMBOL(g_cnt));
    hipGetSymbolAddress((void**)&csr, HIP_SYMBOL(g_csr));

    k_prep<<<(16 * 8 * 64 + N_NODES + 255) / 256, 256, 0, stream>>>(W1l, W1r, cnt);
    k_fill_gemm1<<<FILL_BLOCKS + RGROUPS + PACK2_BLOCKS, 256, 0, stream>>>(
        ei, cnt, csr, x4, W2l, W2r, W3l, W3r);
    k_agg8_l1<<<(N_NODES + 3) / 4, 256, 0, stream>>>(a1, b1);
    k_mgemm2_l<<<RGROUPS, 256, 0, stream>>>();
    k_agg8_l2<<<(N_NODES + 3) / 4, 256, 0, stream>>>(a2, b2);
    k_mgemm3_l<<<RGROUPS, 256, 0, stream>>>();
    k_agg1_l<<<(N_NODES + 3) / 4, 256, 0, stream>>>(a3, b3, out);
}

// Round 5
// 247.118 us; speedup vs baseline: 4.1474x; 4.1474x over previous
//
#include <hip/hip_runtime.h>

#define N_NODES 10000
#define N_EDGES 320000
#define E_TOT   (N_EDGES + N_NODES)
#define HID 256
#define NEG_SLOPE 0.2f
#define SLOTS 192   // fixed CSR slots/node; deg ~ Binom(320k,1e-4), mean 32
#define RGROUPS (N_NODES / 16)   // 625 16-row GEMM groups (exact)

typedef __attribute__((ext_vector_type(8))) short short8;
typedef __attribute__((ext_vector_type(4))) float float4v;

// ---- all scratch in module-scope device globals (no d_ws dependency) ----
__device__ int   g_cnt[N_NODES];
__device__ int   g_csr[(size_t)N_NODES * SLOTS];
__device__ __align__(16) float g_xl[(size_t)N_NODES * HID];
__device__ __align__(16) float g_xr[(size_t)N_NODES * HID];
__device__ __align__(16) float g_h1[(size_t)N_NODES * HID];
__device__ __align__(16) unsigned short g_xlb[(size_t)N_NODES * HID];
__device__ __align__(16) unsigned short g_abf[(size_t)N_NODES * 512];
__device__ __align__(16) unsigned short g_bp1a[16 * 8  * 64 * 8];  // W1l
__device__ __align__(16) unsigned short g_bp2a[16 * 8  * 64 * 8];  // W1r
__device__ __align__(16) unsigned short g_bp1b[16 * 16 * 64 * 8];  // W2l
__device__ __align__(16) unsigned short g_bp2b[16 * 16 * 64 * 8];  // W2r
__device__ __align__(16) unsigned short g_bp1c[2  * 16 * 64 * 8];  // W3l
__device__ __align__(16) unsigned short g_bp2c[2  * 16 * 64 * 8];  // W3r

#define LOG2E 1.44269504088896340736f

// ---------------- bf16 helpers (RNE) ----------------
__device__ __forceinline__ unsigned short f2bf(float f) {
    unsigned int u = __float_as_uint(f);
    unsigned int r = (u + 0x7fffu + ((u >> 16) & 1u)) >> 16;
    return (unsigned short)r;
}
__device__ __forceinline__ float bf2f(unsigned short h) {
    return __uint_as_float(((unsigned int)h) << 16);
}
__device__ __forceinline__ unsigned int splitpack(float f) {
    unsigned short hi = f2bf(f);
    unsigned short lo = f2bf(f - bf2f(hi));
    return ((unsigned int)lo << 16) | hi;   // mem halfwords: [2i]=hi, [2i+1]=lo
}

// pack one weight matrix B[K,N] into per-lane MFMA B-fragments (split-bf16).
__device__ __forceinline__ void packB(const float* __restrict__ B,
                                      unsigned short* __restrict__ Bp,
                                      int t, int nkc, int N) {
    int lane = t & 63;
    int kc   = (t >> 6) % nkc;
    int nt   = (t >> 6) / nkc;
    int n = nt * 16 + (lane & 15);
    int kbase = kc * 32 + (lane >> 4) * 8;
    #pragma unroll
    for (int j = 0; j < 8; ++j) {
        int kp = kbase + j;
        int k  = kp >> 1;
        float f = B[(size_t)k * N + n];
        unsigned short hi = f2bf(f);
        Bp[(size_t)t * 8 + j] = (kp & 1) ? f2bf(f - bf2f(hi)) : hi;
    }
}

// =================== phase device functions ===================

// layer-1 GEMM, one 16-row group: A = x (f32, inline split), dual B (W1l/W1r)
__device__ __forceinline__ void gemm1_tile(int rg, int lane, int wid,
                                           const float4* __restrict__ A4) {
    int quad = lane >> 4, col = lane & 15;
    int arow = rg * 16 + col;
    const float4* a0 = A4 + (size_t)arow * 32;   // 128 f32 = 32 float4
    const short8* Bp1 = (const short8*)g_bp1a;
    const short8* Bp2 = (const short8*)g_bp2a;
    float4v acc[4][2];
    #pragma unroll
    for (int t = 0; t < 4; ++t) { acc[t][0] = (float4v)(0.f); acc[t][1] = (float4v)(0.f); }
    for (int kc = 0; kc < 8; ++kc) {
        float4 v0 = a0[kc * 4 + quad];
        union { short8 s; unsigned int u[4]; } c0;
        c0.u[0] = splitpack(v0.x); c0.u[1] = splitpack(v0.y);
        c0.u[2] = splitpack(v0.z); c0.u[3] = splitpack(v0.w);
        short8 A0 = c0.s;
        #pragma unroll
        for (int t = 0; t < 4; ++t) {
            int nt = wid * 4 + t;
            size_t bi = ((size_t)(nt * 8 + kc)) * 64 + lane;
            acc[t][0] = __builtin_amdgcn_mfma_f32_16x16x32_bf16(A0, Bp1[bi], acc[t][0], 0, 0, 0);
            acc[t][1] = __builtin_amdgcn_mfma_f32_16x16x32_bf16(A0, Bp2[bi], acc[t][1], 0, 0, 0);
        }
    }
    #pragma unroll
    for (int t = 0; t < 4; ++t) {
        int gc = (wid * 4 + t) * 16 + col;
        #pragma unroll
        for (int r = 0; r < 4; ++r) {
            int row = rg * 16 + quad * 4 + r;
            g_xlb[(size_t)row * 256 + gc] = f2bf(acc[t][0][r]);
            g_xr [(size_t)row * 256 + gc] = acc[t][1][r];
        }
    }
}

// layer-2 GEMM, one 16-row group: A = abf (pre-split, Kp=512), dual B (W2l/W2r)
__device__ __forceinline__ void gemm2_tile(int rg, int lane, int wid) {
    int quad = lane >> 4, col = lane & 15;
    int arow = rg * 16 + col;
    const short8* a0 = (const short8*)g_abf + (size_t)arow * 64;  // Kp/8 = 64
    const short8* Bp1 = (const short8*)g_bp1b;
    const short8* Bp2 = (const short8*)g_bp2b;
    float4v acc[4][2];
    #pragma unroll
    for (int t = 0; t < 4; ++t) { acc[t][0] = (float4v)(0.f); acc[t][1] = (float4v)(0.f); }
    for (int kc = 0; kc < 16; ++kc) {
        short8 A0 = a0[kc * 4 + quad];
        #pragma unroll
        for (int t = 0; t < 4; ++t) {
            int nt = wid * 4 + t;
            size_t bi = ((size_t)(nt * 16 + kc)) * 64 + lane;
            acc[t][0] = __builtin_amdgcn_mfma_f32_16x16x32_bf16(A0, Bp1[bi], acc[t][0], 0, 0, 0);
            acc[t][1] = __builtin_amdgcn_mfma_f32_16x16x32_bf16(A0, Bp2[bi], acc[t][1], 0, 0, 0);
        }
    }
    #pragma unroll
    for (int t = 0; t < 4; ++t) {
        int gc = (wid * 4 + t) * 16 + col;
        #pragma unroll
        for (int r = 0; r < 4; ++r) {
            int row = rg * 16 + quad * 4 + r;
            g_xlb[(size_t)row * 256 + gc] = f2bf(acc[t][0][r]);
            g_xr [(size_t)row * 256 + gc] = acc[t][1][r];
        }
    }
}

// layer-3 GEMM, one 16-row group: N=32 per matrix, Kp=512, f32 outputs
__device__ __forceinline__ void gemm3_tile(int rg, int lane, int wid) {
    int quad = lane >> 4, col = lane & 15;
    int nt   = wid & 1;
    const short8* Bp = (wid < 2) ? (const short8*)g_bp1c : (const short8*)g_bp2c;
    float* C = (wid < 2) ? g_xl : g_xr;
    const short8* abase = (const short8*)g_abf + (size_t)(rg * 16 + col) * 64 + quad;
    float4v acc = (float4v)(0.f);
    #pragma unroll 4
    for (int kc = 0; kc < 16; ++kc) {
        short8 a = abase[kc * 4];
        short8 b = Bp[((size_t)(nt * 16 + kc)) * 64 + lane];
        acc = __builtin_amdgcn_mfma_f32_16x16x32_bf16(a, b, acc, 0, 0, 0);
    }
    #pragma unroll
    for (int r = 0; r < 4; ++r)
        C[(size_t)(rg * 16 + quad * 4 + r) * 32 + nt * 16 + col] = acc[r];
}

// GATv2 aggregation, heads=8, one node per wave, 8 edges in flight.
// CSR row address is wave-uniform: readfirstlane forces the node into an
// SGPR so the 8 per-batch index reads become scalar s_loads (SMEM pipe)
// instead of a 64-wide vector preload + 8 ds_bpermute broadcasts (DS pipe).
// Gathers then issue as SGPR-base + lane-offset. Math order unchanged.
template<int MODE>
__device__ __forceinline__ void agg8_node(int node_in, int lane,
                                          const float4* __restrict__ att4,
                                          const float4* __restrict__ bias4) {
    int node = __builtin_amdgcn_readfirstlane(node_in);
    const unsigned short* xlb = g_xlb;
    const float4* xr4 = (const float4*)g_xr;
    float4 xrv = xr4[(size_t)node * 64 + lane];
    float4 av  = att4[lane];
    av.x *= LOG2E; av.y *= LOG2E; av.z *= LOG2E; av.w *= LOG2E;
    int c = g_cnt[node]; if (c > SLOTS) c = SLOTS;
    const int* crow = g_csr + node * SLOTS;

    float s = 0.f;
    float4 acc = make_float4(0.f, 0.f, 0.f, 0.f);

    for (int j0 = 0; j0 < c; j0 += 8) {
        int srcs[8];
        #pragma unroll
        for (int j = 0; j < 8; ++j) {
            // wave-uniform address -> scalar load; clamp stale-tail garbage
            int sv = crow[j0 + j];               // j0+j <= 191 < SLOTS always
            srcs[j] = ((unsigned)sv < N_NODES) ? sv : 0;
        }
        ushort4 uv[8];
        #pragma unroll
        for (int j = 0; j < 8; ++j)
            uv[j] = *(const ushort4*)(xlb + (size_t)srcs[j] * 256 + 4 * lane);
        #pragma unroll
        for (int j = 0; j < 8; ++j) {
            if (j0 + j < c) {
                float4 xv;
                xv.x = bf2f(uv[j].x); xv.y = bf2f(uv[j].y);
                xv.z = bf2f(uv[j].z); xv.w = bf2f(uv[j].w);
                float tx = xv.x + xrv.x, ty = xv.y + xrv.y;
                float tz = xv.z + xrv.z, tw = xv.w + xrv.w;
                float w = fmaxf(tx, NEG_SLOPE * tx) * av.x
                        + fmaxf(ty, NEG_SLOPE * ty) * av.y
                        + fmaxf(tz, NEG_SLOPE * tz) * av.z
                        + fmaxf(tw, NEG_SLOPE * tw) * av.w;
                w += __shfl_xor(w, 1);
                w += __shfl_xor(w, 2);
                w += __shfl_xor(w, 4);
                float p = exp2f(w);
                s += p;
                acc.x += p * xv.x;
                acc.y += p * xv.y;
                acc.z += p * xv.z;
                acc.w += p * xv.w;
            }
        }
    }

    float inv = 1.f / (s + 1e-16f);
    float4 bv = bias4[lane];
    float4 o;
    o.x = acc.x * inv + bv.x; o.y = acc.y * inv + bv.y;
    o.z = acc.z * inv + bv.z; o.w = acc.w * inv + bv.w;
    if (MODE == 0) {
        o.x = fmaxf(o.x, 0.f); o.y = fmaxf(o.y, 0.f);
        o.z = fmaxf(o.z, 0.f); o.w = fmaxf(o.w, 0.f);
        ((float4*)g_h1)[(size_t)node * 64 + lane] = o;
    } else {
        float4 r = ((const float4*)g_h1)[(size_t)node * 64 + lane];
        o.x += r.x; o.y += r.y; o.z += r.z; o.w += r.w;
    }
    uint4 u;
    u.x = splitpack(o.x); u.y = splitpack(o.y);
    u.z = splitpack(o.z); u.w = splitpack(o.w);
    ((uint4*)g_abf)[(size_t)node * 64 + lane] = u;
}

// GATv2 aggregation, heads=1, one node per wave (8 lane-groups, 2-deep)
__device__ __forceinline__ void agg1_node(int node, int lane,
                                          const float4* __restrict__ att4,
                                          const float4* __restrict__ bias4,
                                          float4* __restrict__ out4) {
    const float4* xl4 = (const float4*)g_xl;
    const float4* xr4 = (const float4*)g_xr;
    int q = lane & 7;
    int grp = lane >> 3;
    float4 xrv = xr4[(size_t)node * 8 + q];
    float4 av  = att4[q];
    av.x *= LOG2E; av.y *= LOG2E; av.z *= LOG2E; av.w *= LOG2E;
    int c = g_cnt[node]; if (c > SLOTS) c = SLOTS;
    int start = node * SLOTS, end = start + c;
    float s = 0.f;
    float4 acc = make_float4(0.f, 0.f, 0.f, 0.f);
    for (int i = start + grp; i < end; i += 16) {
        int i2 = i + 8;
        bool has2 = i2 < end;
        int src0 = g_csr[i];
        int src1 = g_csr[has2 ? i2 : i];
        float4 xv0 = xl4[(size_t)src0 * 8 + q];
        float4 xv1 = xl4[(size_t)src1 * 8 + q];
        {
            float tx = xv0.x + xrv.x, ty = xv0.y + xrv.y;
            float tz = xv0.z + xrv.z, tw = xv0.w + xrv.w;
            float w = fmaxf(tx, NEG_SLOPE * tx) * av.x
                    + fmaxf(ty, NEG_SLOPE * ty) * av.y
                    + fmaxf(tz, NEG_SLOPE * tz) * av.z
                    + fmaxf(tw, NEG_SLOPE * tw) * av.w;
            w += __shfl_xor(w, 1);
            w += __shfl_xor(w, 2);
            w += __shfl_xor(w, 4);
            float p = exp2f(w);
            s += p;
            acc.x += p * xv0.x; acc.y += p * xv0.y;
            acc.z += p * xv0.z; acc.w += p * xv0.w;
        }
        if (has2) {
            float tx = xv1.x + xrv.x, ty = xv1.y + xrv.y;
            float tz = xv1.z + xrv.z, tw = xv1.w + xrv.w;
            float w = fmaxf(tx, NEG_SLOPE * tx) * av.x
                    + fmaxf(ty, NEG_SLOPE * ty) * av.y
                    + fmaxf(tz, NEG_SLOPE * tz) * av.z
                    + fmaxf(tw, NEG_SLOPE * tw) * av.w;
            w += __shfl_xor(w, 1);
            w += __shfl_xor(w, 2);
            w += __shfl_xor(w, 4);
            float p = exp2f(w);
            s += p;
            acc.x += p * xv1.x; acc.y += p * xv1.y;
            acc.z += p * xv1.z; acc.w += p * xv1.w;
        }
    }
    #pragma unroll
    for (int off = 8; off < 64; off <<= 1) {
        s     += __shfl_xor(s, off);
        acc.x += __shfl_xor(acc.x, off);
        acc.y += __shfl_xor(acc.y, off);
        acc.z += __shfl_xor(acc.z, off);
        acc.w += __shfl_xor(acc.w, off);
    }
    if (grp == 0) {
        float inv = 1.f / (s + 1e-16f);
        float4 bv = bias4[q];
        float4 o;
        o.x = acc.x * inv + bv.x; o.y = acc.y * inv + bv.y;
        o.z = acc.z * inv + bv.z; o.w = acc.w * inv + bv.w;
        out4[(size_t)node * 8 + q] = o;
    }
}

// ==================== the 7-kernel chain ======================

__global__ __launch_bounds__(256) void k_prep(const float* __restrict__ W1l,
                                              const float* __restrict__ W1r,
                                              int* __restrict__ cnt) {
    const int S0 = 16 * 8 * 64;
    int t = blockIdx.x * blockDim.x + threadIdx.x;
    if (t < S0) {
        packB(W1l, g_bp1a, t, 8, 256);
        packB(W1r, g_bp2a, t, 8, 256);
    } else {
        int u = t - S0;
        if (u < N_NODES) cnt[u] = 0;
    }
}

#define FILL_BLOCKS  ((E_TOT + 255) / 256)
#define PACK2_BLOCKS ((16 * 16 * 64 + 2 * 16 * 64 + 255) / 256)
__global__ __launch_bounds__(256) void k_fill_gemm1(
    const int* __restrict__ ei,
    int* __restrict__ cnt, int* __restrict__ csr,
    const float4* __restrict__ A4,
    const float* __restrict__ W2l, const float* __restrict__ W2r,
    const float* __restrict__ W3l, const float* __restrict__ W3r)
{
    if (blockIdx.x < FILL_BLOCKS) {
        int e = blockIdx.x * 256 + threadIdx.x;
        if (e < E_TOT) {
            int src, dst;
            if (e < N_EDGES) { src = ei[e]; dst = ei[N_EDGES + e]; }
            else             { src = dst = e - N_EDGES; }
            int pos = atomicAdd(&cnt[dst], 1);
            if (pos < SLOTS) csr[dst * SLOTS + pos] = src;
        }
        return;
    }
    if (blockIdx.x >= FILL_BLOCKS + RGROUPS) {
        const int S1 = 16 * 16 * 64, S2 = 2 * 16 * 64;
        int t = (blockIdx.x - FILL_BLOCKS - RGROUPS) * 256 + threadIdx.x;
        if (t < S1) {
            packB(W2l, g_bp1b, t, 16, 256);
            packB(W2r, g_bp2b, t, 16, 256);
        } else {
            int u = t - S1;
            if (u < S2) {
                packB(W3l, g_bp1c, u, 16, 32);
                packB(W3r, g_bp2c, u, 16, 32);
            }
        }
        return;
    }
    gemm1_tile(blockIdx.x - FILL_BLOCKS, threadIdx.x & 63, threadIdx.x >> 6, A4);
}

__global__ __launch_bounds__(256) void k_mgemm2_l() {
    gemm2_tile(blockIdx.x, threadIdx.x & 63, threadIdx.x >> 6);
}
__global__ __launch_bounds__(256) void k_mgemm3_l() {
    gemm3_tile(blockIdx.x, threadIdx.x & 63, threadIdx.x >> 6);
}
__global__ __launch_bounds__(256) void k_agg8_l1(const float4* __restrict__ att4,
                                                 const float4* __restrict__ bias4) {
    int node = blockIdx.x * 4 + (threadIdx.x >> 6);
    if (node >= N_NODES) return;
    agg8_node<0>(node, threadIdx.x & 63, att4, bias4);
}
__global__ __launch_bounds__(256) void k_agg8_l2(const float4* __restrict__ att4,
                                                 const float4* __restrict__ bias4) {
    int node = blockIdx.x * 4 + (threadIdx.x >> 6);
    if (node >= N_NODES) return;
    agg8_node<1>(node, threadIdx.x & 63, att4, bias4);
}
__global__ __launch_bounds__(256) void k_agg1_l(const float4* __restrict__ att4,
                                                const float4* __restrict__ bias4,
                                                float4* __restrict__ out4) {
    int node = blockIdx.x * 4 + (threadIdx.x >> 6);
    if (node >= N_NODES) return;
    agg1_node(node, threadIdx.x & 63, att4, bias4, out4);
}

// -------------------------------- launch --------------------------------

extern "C" void kernel_launch(void* const* d_in, const int* in_sizes, int n_in,
                              void* d_out, int out_size, void* d_ws, size_t ws_size,
                              hipStream_t stream) {
    const float4* x4 = (const float4*)d_in[0];
    const float* W1l = (const float*)d_in[1];
    const float* W1r = (const float*)d_in[2];
    const float4* a1 = (const float4*)d_in[3];
    const float4* b1 = (const float4*)d_in[4];
    const float* W2l = (const float*)d_in[5];
    const float* W2r = (const float*)d_in[6];
    const float4* a2 = (const float4*)d_in[7];
    const float4* b2 = (const float4*)d_in[8];
    const float* W3l = (const float*)d_in[9];
    const float* W3r = (const float*)d_in[10];
    const float4* a3 = (const float4*)d_in[11];
    const float4* b3 = (const float4*)d_in[12];
    const int*   ei  = (const int*)d_in[13];   // int32! harness converts int64 -> int32
    float4* out = (float4*)d_out;

    int* cnt; int* csr;
    hipGetSymbolAddress((void**)&cnt, HIP_SYMBOL(g_cnt));
    hipGetSymbolAddress((void**)&csr, HIP_SYMBOL(g_csr));

    k_prep<<<(16 * 8 * 64 + N_NODES + 255) / 256, 256, 0, stream>>>(W1l, W1r, cnt);
    k_fill_gemm1<<<FILL_BLOCKS + RGROUPS + PACK2_BLOCKS, 256, 0, stream>>>(
        ei, cnt, csr, x4, W2l, W2r, W3l, W3r);
    k_agg8_l1<<<(N_NODES + 3) / 4, 256, 0, stream>>>(a1, b1);
    k_mgemm2_l<<<RGROUPS, 256, 0, stream>>>();
    k_agg8_l2<<<(N_NODES + 3) / 4, 256, 0, stream>>>(a2, b2);
    k_mgemm3_l<<<RGROUPS, 256, 0, stream>>>();
    k_agg1_l<<<(N_NODES + 3) / 4, 256, 0, stream>>>(a3, b3, out);
}

// Round 6
// 241.887 us; speedup vs baseline: 4.2371x; 1.0216x over previous
//
#include <hip/hip_runtime.h>

#define N_NODES 10000
#define N_EDGES 320000
#define E_TOT   (N_EDGES + N_NODES)
#define HID 256
#define NEG_SLOPE 0.2f
#define SLOTS 192   // fixed CSR slots/node; deg ~ Binom(320k,1e-4), mean 32

typedef __attribute__((ext_vector_type(8))) short short8;
typedef __attribute__((ext_vector_type(4))) float float4v;

// ---- all scratch in module-scope device globals (no d_ws dependency) ----
__device__ int   g_cnt[N_NODES];
__device__ int   g_csr[(size_t)N_NODES * SLOTS];
__device__ __align__(16) float g_xl[(size_t)N_NODES * HID];   // f32 (layer-3 use)
__device__ __align__(16) float g_xr[(size_t)N_NODES * HID];
__device__ __align__(16) float g_h1[(size_t)N_NODES * HID];
__device__ __align__(16) unsigned short g_xlb[(size_t)N_NODES * HID];  // bf16 xl (gather payload)
__device__ __align__(16) unsigned short g_abf[(size_t)N_NODES * 512];
__device__ __align__(16) unsigned short g_bp1a[16 * 8  * 64 * 8];  // W1l
__device__ __align__(16) unsigned short g_bp2a[16 * 8  * 64 * 8];  // W1r
__device__ __align__(16) unsigned short g_bp1b[16 * 16 * 64 * 8];  // W2l
__device__ __align__(16) unsigned short g_bp2b[16 * 16 * 64 * 8];  // W2r
__device__ __align__(16) unsigned short g_bp1c[2  * 16 * 64 * 8];  // W3l
__device__ __align__(16) unsigned short g_bp2c[2  * 16 * 64 * 8];  // W3r

#define LOG2E 1.44269504088896340736f

// ---------------- bf16 helpers (RNE) ----------------
__device__ __forceinline__ unsigned short f2bf(float f) {
    unsigned int u = __float_as_uint(f);
    unsigned int r = (u + 0x7fffu + ((u >> 16) & 1u)) >> 16;
    return (unsigned short)r;
}
__device__ __forceinline__ float bf2f(unsigned short h) {
    return __uint_as_float(((unsigned int)h) << 16);
}
__device__ __forceinline__ unsigned int splitpack(float f) {
    unsigned short hi = f2bf(f);
    unsigned short lo = f2bf(f - bf2f(hi));
    return ((unsigned int)lo << 16) | hi;   // mem halfwords: [2i]=hi, [2i+1]=lo
}

// pack one weight matrix B[K,N] into per-lane MFMA B-fragments (split-bf16).
__device__ __forceinline__ void packB(const float* __restrict__ B,
                                      unsigned short* __restrict__ Bp,
                                      int t, int nkc, int N) {
    int lane = t & 63;
    int kc   = (t >> 6) % nkc;
    int nt   = (t >> 6) / nkc;
    int n = nt * 16 + (lane & 15);
    int kbase = kc * 32 + (lane >> 4) * 8;
    #pragma unroll
    for (int j = 0; j < 8; ++j) {
        int kp = kbase + j;
        int k  = kp >> 1;
        float f = B[(size_t)k * N + n];
        unsigned short hi = f2bf(f);
        Bp[(size_t)t * 8 + j] = (kp & 1) ? f2bf(f - bf2f(hi)) : hi;
    }
}

// ---- prep: pack layer-1 weights + zero the slot counters ----
__global__ __launch_bounds__(256) void k_prep(const float* __restrict__ W1l,
                                              const float* __restrict__ W1r,
                                              int* __restrict__ cnt) {
    const int S0 = 16 * 8 * 64;    // 8192
    int t = blockIdx.x * blockDim.x + threadIdx.x;
    if (t < S0) {
        packB(W1l, g_bp1a, t, 8, 256);
        packB(W1r, g_bp2a, t, 8, 256);
    } else {
        int u = t - S0;
        if (u < N_NODES) cnt[u] = 0;
    }
}

// ==== fill CSR slots + layer-1 dual GEMM (32-row tiles) + W2/W3 packing ==
#define FILL_BLOCKS  ((E_TOT + 255) / 256)     // 1290
#define GEMM1_BLOCKS ((N_NODES + 31) / 32)     // 313
#define PACK2_BLOCKS ((16 * 16 * 64 + 2 * 16 * 64 + 255) / 256)  // 72
__global__ __launch_bounds__(256) void k_fill_gemm1(
    const int* __restrict__ ei,
    int* __restrict__ cnt, int* __restrict__ csr,
    const float4* __restrict__ A4,          // x, [N,128] f32
    const float* __restrict__ W2l, const float* __restrict__ W2r,
    const float* __restrict__ W3l, const float* __restrict__ W3r)
{
    if (blockIdx.x < FILL_BLOCKS) {
        int e = blockIdx.x * 256 + threadIdx.x;
        if (e < E_TOT) {
            int src, dst;
            if (e < N_EDGES) { src = ei[e]; dst = ei[N_EDGES + e]; }
            else             { src = dst = e - N_EDGES; }
            int pos = atomicAdd(&cnt[dst], 1);
            if (pos < SLOTS) csr[dst * SLOTS + pos] = src;
        }
        return;
    }
    if (blockIdx.x >= FILL_BLOCKS + GEMM1_BLOCKS) {
        const int S1 = 16 * 16 * 64;   // 16384
        const int S2 = 2 * 16 * 64;    // 2048
        int t = (blockIdx.x - FILL_BLOCKS - GEMM1_BLOCKS) * 256 + threadIdx.x;
        if (t < S1) {
            packB(W2l, g_bp1b, t, 16, 256);
            packB(W2r, g_bp2b, t, 16, 256);
        } else {
            int u = t - S1;
            if (u < S2) {
                packB(W3l, g_bp1c, u, 16, 32);
                packB(W3r, g_bp2c, u, 16, 32);
            }
        }
        return;
    }
    // ---- layer-1 dual GEMM: 32-row tiles, K=128 f32 inline split ----
    const int nkc = 8;                   // Kp = 256
    int mt   = blockIdx.x - FILL_BLOCKS;
    int lane = threadIdx.x & 63;
    int wid  = threadIdx.x >> 6;
    int quad = lane >> 4;
    int col  = lane & 15;
    const short8* Bp1 = (const short8*)g_bp1a;
    const short8* Bp2 = (const short8*)g_bp2a;
    int r0 = mt * 32 + col;       if (r0 >= N_NODES) r0 = N_NODES - 1;
    int r1 = mt * 32 + 16 + col;  if (r1 >= N_NODES) r1 = N_NODES - 1;
    const float4* a0 = A4 + (size_t)r0 * 32 + quad;   // K/4 = 32
    const float4* a1 = A4 + (size_t)r1 * 32 + quad;
    float4v acc[2][4][2];
    #pragma unroll
    for (int s = 0; s < 2; ++s)
        #pragma unroll
        for (int t = 0; t < 4; ++t) { acc[s][t][0] = (float4v)(0.f); acc[s][t][1] = (float4v)(0.f); }
    for (int kc = 0; kc < nkc; ++kc) {
        float4 v0 = a0[kc * 4];
        float4 v1 = a1[kc * 4];
        union { short8 s; unsigned int u[4]; } c0, c1;
        c0.u[0] = splitpack(v0.x); c0.u[1] = splitpack(v0.y);
        c0.u[2] = splitpack(v0.z); c0.u[3] = splitpack(v0.w);
        c1.u[0] = splitpack(v1.x); c1.u[1] = splitpack(v1.y);
        c1.u[2] = splitpack(v1.z); c1.u[3] = splitpack(v1.w);
        short8 A0 = c0.s, A1 = c1.s;
        #pragma unroll
        for (int t = 0; t < 4; ++t) {
            int nt = wid * 4 + t;
            size_t bi = ((size_t)(nt * nkc + kc)) * 64 + lane;
            short8 b1 = Bp1[bi];
            short8 b2 = Bp2[bi];
            acc[0][t][0] = __builtin_amdgcn_mfma_f32_16x16x32_bf16(A0, b1, acc[0][t][0], 0, 0, 0);
            acc[0][t][1] = __builtin_amdgcn_mfma_f32_16x16x32_bf16(A0, b2, acc[0][t][1], 0, 0, 0);
            acc[1][t][0] = __builtin_amdgcn_mfma_f32_16x16x32_bf16(A1, b1, acc[1][t][0], 0, 0, 0);
            acc[1][t][1] = __builtin_amdgcn_mfma_f32_16x16x32_bf16(A1, b2, acc[1][t][1], 0, 0, 0);
        }
    }
    #pragma unroll
    for (int s = 0; s < 2; ++s) {
        #pragma unroll
        for (int t = 0; t < 4; ++t) {
            int gc = (wid * 4 + t) * 16 + col;
            #pragma unroll
            for (int r = 0; r < 4; ++r) {
                int row = mt * 32 + s * 16 + quad * 4 + r;
                if (row < N_NODES) {
                    g_xlb[(size_t)row * 256 + gc] = f2bf(acc[s][t][0][r]);
                    g_xr [(size_t)row * 256 + gc] = acc[s][t][1][r];
                }
            }
        }
    }
}

// ---------- MFMA split-bf16 dual GEMM (A=abf pre-split, Kp=512): N=256 ----
__global__ __launch_bounds__(256) void k_mgemm2() {
    const int nkc = 16;
    int mt   = blockIdx.x;
    int lane = threadIdx.x & 63;
    int wid  = threadIdx.x >> 6;
    int quad = lane >> 4;
    int col  = lane & 15;
    const short8* Af  = (const short8*)g_abf;
    const short8* Bp1 = (const short8*)g_bp1b;
    const short8* Bp2 = (const short8*)g_bp2b;
    int r0 = mt * 32 + col;       if (r0 >= N_NODES) r0 = N_NODES - 1;
    int r1 = mt * 32 + 16 + col;  if (r1 >= N_NODES) r1 = N_NODES - 1;
    const short8* a0 = Af + (size_t)r0 * 64 + quad;
    const short8* a1 = Af + (size_t)r1 * 64 + quad;
    float4v acc[2][4][2];
    #pragma unroll
    for (int s = 0; s < 2; ++s)
        #pragma unroll
        for (int t = 0; t < 4; ++t) { acc[s][t][0] = (float4v)(0.f); acc[s][t][1] = (float4v)(0.f); }
    for (int kc = 0; kc < nkc; ++kc) {
        short8 A0 = a0[kc * 4];
        short8 A1 = a1[kc * 4];
        #pragma unroll
        for (int t = 0; t < 4; ++t) {
            int nt = wid * 4 + t;
            size_t bi = ((size_t)(nt * nkc + kc)) * 64 + lane;
            short8 b1 = Bp1[bi];
            short8 b2 = Bp2[bi];
            acc[0][t][0] = __builtin_amdgcn_mfma_f32_16x16x32_bf16(A0, b1, acc[0][t][0], 0, 0, 0);
            acc[0][t][1] = __builtin_amdgcn_mfma_f32_16x16x32_bf16(A0, b2, acc[0][t][1], 0, 0, 0);
            acc[1][t][0] = __builtin_amdgcn_mfma_f32_16x16x32_bf16(A1, b1, acc[1][t][0], 0, 0, 0);
            acc[1][t][1] = __builtin_amdgcn_mfma_f32_16x16x32_bf16(A1, b2, acc[1][t][1], 0, 0, 0);
        }
    }
    #pragma unroll
    for (int s = 0; s < 2; ++s) {
        #pragma unroll
        for (int t = 0; t < 4; ++t) {
            int gc = (wid * 4 + t) * 16 + col;
            #pragma unroll
            for (int r = 0; r < 4; ++r) {
                int row = mt * 32 + s * 16 + quad * 4 + r;
                if (row < N_NODES) {
                    g_xlb[(size_t)row * 256 + gc] = f2bf(acc[s][t][0][r]);
                    g_xr [(size_t)row * 256 + gc] = acc[s][t][1][r];
                }
            }
        }
    }
}

// ---------- MFMA dual GEMM, layer 3: N=32, Kp=512 (f32 outputs) ----------
__global__ __launch_bounds__(256) void k_mgemm32() {
    int mt   = blockIdx.x;
    int lane = threadIdx.x & 63;
    int wid  = threadIdx.x >> 6;
    int quad = lane >> 4;
    int col  = lane & 15;
    int nt   = wid & 1;
    const short8* Bp = (wid < 2) ? (const short8*)g_bp1c : (const short8*)g_bp2c;
    float* C = (wid < 2) ? g_xl : g_xr;

    const short8* abase = (const short8*)g_abf + (size_t)(mt * 16 + col) * 64 + quad;
    float4v acc = (float4v)(0.f);
    #pragma unroll 4
    for (int kc = 0; kc < 16; ++kc) {
        short8 a = abase[kc * 4];
        short8 b = Bp[((size_t)(nt * 16 + kc)) * 64 + lane];
        acc = __builtin_amdgcn_mfma_f32_16x16x32_bf16(a, b, acc, 0, 0, 0);
    }
    #pragma unroll
    for (int r = 0; r < 4; ++r)
        C[(size_t)(mt * 16 + quad * 4 + r) * 32 + nt * 16 + col] = acc[r];
}

// ---- GATv2 agg, heads=8, HEAD-SPLIT pass (PASS=0: ch0-127, PASS=1: ch128-255)
// Wave per node; 32 lanes per edge (4ch/lane), two edges per wave step,
// 4 pair-loads (8 edges) in flight. Per-pass gather set = 2.56MB < 4MB
// per-XCD L2 (full 5MB row set thrashes it -> L3 latency; that was the
// round-2-diagnosed stall). Per-head score = identical 8-lane xor-tree.
template<int MODE, int PASS>
__global__ __launch_bounds__(256) void k_agg8h(const float4* __restrict__ att4,
                                               const float4* __restrict__ bias4) {
    int node = blockIdx.x * 4 + (threadIdx.x >> 6);
    if (node >= N_NODES) return;
    int lane = threadIdx.x & 63;
    int hl   = lane & 31;
    int half = lane >> 5;
    float4 xrv = ((const float4*)g_xr)[(size_t)node * 64 + PASS * 32 + hl];
    float4 av  = att4[PASS * 32 + hl];
    av.x *= LOG2E; av.y *= LOG2E; av.z *= LOG2E; av.w *= LOG2E;
    int c = g_cnt[node]; if (c > SLOTS) c = SLOTS;
    int base0 = node * SLOTS;

    float s = 0.f;
    float4 acc = make_float4(0.f, 0.f, 0.f, 0.f);

    for (int base = 0; base < c; base += 64) {
        int li = base + lane;
        int idxv = g_csr[base0 + (li < c ? li : c - 1)];
        int m = c - base; if (m > 64) m = 64;
        for (int j0 = 0; j0 < m; j0 += 8) {
            int srcs[4];
            ushort4 uv[4];
            #pragma unroll
            for (int k = 0; k < 4; ++k)
                srcs[k] = __shfl(idxv, j0 + 2 * k + half);
            #pragma unroll
            for (int k = 0; k < 4; ++k)
                uv[k] = *(const ushort4*)(g_xlb + (size_t)srcs[k] * 256 + PASS * 128 + 4 * hl);
            #pragma unroll
            for (int k = 0; k < 4; ++k) {
                if (j0 + 2 * k + half < m) {
                    float4 xv;
                    xv.x = bf2f(uv[k].x); xv.y = bf2f(uv[k].y);
                    xv.z = bf2f(uv[k].z); xv.w = bf2f(uv[k].w);
                    float tx = xv.x + xrv.x, ty = xv.y + xrv.y;
                    float tz = xv.z + xrv.z, tw = xv.w + xrv.w;
                    float w = fmaxf(tx, NEG_SLOPE * tx) * av.x
                            + fmaxf(ty, NEG_SLOPE * ty) * av.y
                            + fmaxf(tz, NEG_SLOPE * tz) * av.z
                            + fmaxf(tw, NEG_SLOPE * tw) * av.w;
                    w += __shfl_xor(w, 1);
                    w += __shfl_xor(w, 2);
                    w += __shfl_xor(w, 4);
                    float p = exp2f(w);
                    s += p;
                    acc.x += p * xv.x;
                    acc.y += p * xv.y;
                    acc.z += p * xv.z;
                    acc.w += p * xv.w;
                }
            }
        }
    }

    // combine even/odd edge halves
    s += __shfl_xor(s, 32);
    acc.x += __shfl_xor(acc.x, 32);
    acc.y += __shfl_xor(acc.y, 32);
    acc.z += __shfl_xor(acc.z, 32);
    acc.w += __shfl_xor(acc.w, 32);

    float inv = 1.f / (s + 1e-16f);
    float4 bv = bias4[PASS * 32 + hl];
    float4 o;
    o.x = acc.x * inv + bv.x; o.y = acc.y * inv + bv.y;
    o.z = acc.z * inv + bv.z; o.w = acc.w * inv + bv.w;
    if (MODE == 0) {
        o.x = fmaxf(o.x, 0.f); o.y = fmaxf(o.y, 0.f);
        o.z = fmaxf(o.z, 0.f); o.w = fmaxf(o.w, 0.f);
    } else {
        float4 r = ((const float4*)g_h1)[(size_t)node * 64 + PASS * 32 + hl];
        o.x += r.x; o.y += r.y; o.z += r.z; o.w += r.w;
    }
    if (half == 0) {
        if (MODE == 0)
            ((float4*)g_h1)[(size_t)node * 64 + PASS * 32 + hl] = o;
        uint4 u;
        u.x = splitpack(o.x); u.y = splitpack(o.y);
        u.z = splitpack(o.z); u.w = splitpack(o.w);
        ((uint4*)g_abf)[(size_t)node * 64 + PASS * 32 + hl] = u;
    }
}

// ------------- GATv2 attention + aggregation, heads=1, ch=32 -------------
__global__ __launch_bounds__(256) void k_agg1(const float4* __restrict__ att4,
                                              const float4* __restrict__ bias4,
                                              float4* __restrict__ out4) {
    int node = blockIdx.x * 4 + (threadIdx.x >> 6);
    if (node >= N_NODES) return;
    int lane = threadIdx.x & 63;
    int q = lane & 7;
    int grp = lane >> 3;
    const float4* xl4 = (const float4*)g_xl;
    const float4* xr4 = (const float4*)g_xr;
    float4 xrv = xr4[(size_t)node * 8 + q];
    float4 av  = att4[q];
    av.x *= LOG2E; av.y *= LOG2E; av.z *= LOG2E; av.w *= LOG2E;
    int c = g_cnt[node]; if (c > SLOTS) c = SLOTS;
    int start = node * SLOTS, end = start + c;
    float s = 0.f;
    float4 acc = make_float4(0.f, 0.f, 0.f, 0.f);
    for (int i = start + grp; i < end; i += 16) {
        int i2 = i + 8;
        bool has2 = i2 < end;
        int src0 = g_csr[i];
        int src1 = g_csr[has2 ? i2 : i];
        float4 xv0 = xl4[(size_t)src0 * 8 + q];
        float4 xv1 = xl4[(size_t)src1 * 8 + q];
        {
            float tx = xv0.x + xrv.x, ty = xv0.y + xrv.y;
            float tz = xv0.z + xrv.z, tw = xv0.w + xrv.w;
            float w = fmaxf(tx, NEG_SLOPE * tx) * av.x
                    + fmaxf(ty, NEG_SLOPE * ty) * av.y
                    + fmaxf(tz, NEG_SLOPE * tz) * av.z
                    + fmaxf(tw, NEG_SLOPE * tw) * av.w;
            w += __shfl_xor(w, 1);
            w += __shfl_xor(w, 2);
            w += __shfl_xor(w, 4);
            float p = exp2f(w);
            s += p;
            acc.x += p * xv0.x; acc.y += p * xv0.y;
            acc.z += p * xv0.z; acc.w += p * xv0.w;
        }
        if (has2) {
            float tx = xv1.x + xrv.x, ty = xv1.y + xrv.y;
            float tz = xv1.z + xrv.z, tw = xv1.w + xrv.w;
            float w = fmaxf(tx, NEG_SLOPE * tx) * av.x
                    + fmaxf(ty, NEG_SLOPE * ty) * av.y
                    + fmaxf(tz, NEG_SLOPE * tz) * av.z
                    + fmaxf(tw, NEG_SLOPE * tw) * av.w;
            w += __shfl_xor(w, 1);
            w += __shfl_xor(w, 2);
            w += __shfl_xor(w, 4);
            float p = exp2f(w);
            s += p;
            acc.x += p * xv1.x; acc.y += p * xv1.y;
            acc.z += p * xv1.z; acc.w += p * xv1.w;
        }
    }
    #pragma unroll
    for (int off = 8; off < 64; off <<= 1) {
        s     += __shfl_xor(s, off);
        acc.x += __shfl_xor(acc.x, off);
        acc.y += __shfl_xor(acc.y, off);
        acc.z += __shfl_xor(acc.z, off);
        acc.w += __shfl_xor(acc.w, off);
    }
    if (grp == 0) {
        float inv = 1.f / (s + 1e-16f);
        float4 bv = bias4[q];
        float4 o;
        o.x = acc.x * inv + bv.x; o.y = acc.y * inv + bv.y;
        o.z = acc.z * inv + bv.z; o.w = acc.w * inv + bv.w;
        out4[(size_t)node * 8 + q] = o;
    }
}

// -------------------------------- launch --------------------------------

extern "C" void kernel_launch(void* const* d_in, const int* in_sizes, int n_in,
                              void* d_out, int out_size, void* d_ws, size_t ws_size,
                              hipStream_t stream) {
    const float4* x4 = (const float4*)d_in[0];
    const float* W1l = (const float*)d_in[1];
    const float* W1r = (const float*)d_in[2];
    const float4* a1 = (const float4*)d_in[3];
    const float4* b1 = (const float4*)d_in[4];
    const float* W2l = (const float*)d_in[5];
    const float* W2r = (const float*)d_in[6];
    const float4* a2 = (const float4*)d_in[7];
    const float4* b2 = (const float4*)d_in[8];
    const float* W3l = (const float*)d_in[9];
    const float* W3r = (const float*)d_in[10];
    const float4* a3 = (const float4*)d_in[11];
    const float4* b3 = (const float4*)d_in[12];
    const int*   ei  = (const int*)d_in[13];   // int32! harness converts int64 -> int32
    float4* out = (float4*)d_out;

    int* cnt; int* csr;
    hipGetSymbolAddress((void**)&cnt, HIP_SYMBOL(g_cnt));
    hipGetSymbolAddress((void**)&csr, HIP_SYMBOL(g_csr));

    const int AGG_BLOCKS = (N_NODES + 3) / 4;

    // 1: pack W1 + zero slot counters
    k_prep<<<(16 * 8 * 64 + N_NODES + 255) / 256, 256, 0, stream>>>(W1l, W1r, cnt);

    // 2: CSR fill + layer-1 dual GEMM (32-row tiles) + W2/W3 packing
    k_fill_gemm1<<<FILL_BLOCKS + GEMM1_BLOCKS + PACK2_BLOCKS, 256, 0, stream>>>(
        ei, cnt, csr, x4, W2l, W2r, W3l, W3r);

    // 3-4: layer-1 aggregation, head-split (L2-resident gather per pass)
    k_agg8h<0, 0><<<AGG_BLOCKS, 256, 0, stream>>>(a1, b1);
    k_agg8h<0, 1><<<AGG_BLOCKS, 256, 0, stream>>>(a1, b1);

    // 5: layer-2 dual GEMM (Kp=512 from abf)
    k_mgemm2<<<GEMM1_BLOCKS, 256, 0, stream>>>();

    // 6-7: layer-2 aggregation (+ residual), head-split
    k_agg8h<1, 0><<<AGG_BLOCKS, 256, 0, stream>>>(a2, b2);
    k_agg8h<1, 1><<<AGG_BLOCKS, 256, 0, stream>>>(a2, b2);

    // 8: layer-3 dual GEMM (N=32)
    k_mgemm32<<<N_NODES / 16, 256, 0, stream>>>();

    // 9: heads=1 aggregation -> output
    k_agg1<<<AGG_BLOCKS, 256, 0, stream>>>(a3, b3, out);
}

// Round 7
// 223.997 us; speedup vs baseline: 4.5755x; 1.0799x over previous
//
#include <hip/hip_runtime.h>

#define N_NODES 10000
#define N_EDGES 320000
#define E_TOT   (N_EDGES + N_NODES)
#define HID 256
#define NEG_SLOPE 0.2f
#define SLOTS 192   // fixed CSR slots/node; deg ~ Binom(320k,1e-4), mean 32

typedef __attribute__((ext_vector_type(8))) short short8;
typedef __attribute__((ext_vector_type(4))) float float4v;

// ---- all scratch in module-scope device globals (no d_ws dependency) ----
__device__ int   g_cnt[N_NODES];
__device__ int   g_csr[(size_t)N_NODES * SLOTS];
__device__ __align__(16) float g_xl[(size_t)N_NODES * HID];   // f32 (layer-3 use)
__device__ __align__(16) float g_xr[(size_t)N_NODES * HID];
__device__ __align__(16) float g_h1[(size_t)N_NODES * HID];
__device__ __align__(16) unsigned short g_xlb[(size_t)N_NODES * HID];  // bf16 xl (gather payload)
__device__ __align__(16) unsigned short g_abf[(size_t)N_NODES * 512];
__device__ __align__(16) unsigned short g_bp1a[16 * 8  * 64 * 8];  // W1l
__device__ __align__(16) unsigned short g_bp2a[16 * 8  * 64 * 8];  // W1r
__device__ __align__(16) unsigned short g_bp1b[16 * 16 * 64 * 8];  // W2l
__device__ __align__(16) unsigned short g_bp2b[16 * 16 * 64 * 8];  // W2r
__device__ __align__(16) unsigned short g_bp1c[2  * 16 * 64 * 8];  // W3l
__device__ __align__(16) unsigned short g_bp2c[2  * 16 * 64 * 8];  // W3r

#define LOG2E 1.44269504088896340736f

// ---------------- bf16 helpers (RNE) ----------------
__device__ __forceinline__ unsigned short f2bf(float f) {
    unsigned int u = __float_as_uint(f);
    unsigned int r = (u + 0x7fffu + ((u >> 16) & 1u)) >> 16;
    return (unsigned short)r;
}
__device__ __forceinline__ float bf2f(unsigned short h) {
    return __uint_as_float(((unsigned int)h) << 16);
}
__device__ __forceinline__ unsigned int splitpack(float f) {
    unsigned short hi = f2bf(f);
    unsigned short lo = f2bf(f - bf2f(hi));
    return ((unsigned int)lo << 16) | hi;   // mem halfwords: [2i]=hi, [2i+1]=lo
}

// pack one weight matrix B[K,N] into per-lane MFMA B-fragments (split-bf16).
__device__ __forceinline__ void packB(const float* __restrict__ B,
                                      unsigned short* __restrict__ Bp,
                                      int t, int nkc, int N) {
    int lane = t & 63;
    int kc   = (t >> 6) % nkc;
    int nt   = (t >> 6) / nkc;
    int n = nt * 16 + (lane & 15);
    int kbase = kc * 32 + (lane >> 4) * 8;
    #pragma unroll
    for (int j = 0; j < 8; ++j) {
        int kp = kbase + j;
        int k  = kp >> 1;
        float f = B[(size_t)k * N + n];
        unsigned short hi = f2bf(f);
        Bp[(size_t)t * 8 + j] = (kp & 1) ? f2bf(f - bf2f(hi)) : hi;
    }
}

// ---- prep: pack all six weight matrices + zero the slot counters ----
__global__ __launch_bounds__(256) void k_prep(const float* __restrict__ W1l,
                                              const float* __restrict__ W1r,
                                              const float* __restrict__ W2l,
                                              const float* __restrict__ W2r,
                                              const float* __restrict__ W3l,
                                              const float* __restrict__ W3r,
                                              int* __restrict__ cnt) {
    const int S0 = 16 * 8 * 64;    // 8192
    const int S1 = 16 * 16 * 64;   // 16384
    const int S2 = 2 * 16 * 64;    // 2048
    int t = blockIdx.x * blockDim.x + threadIdx.x;
    if (t < S0) {
        packB(W1l, g_bp1a, t, 8, 256);
        packB(W1r, g_bp2a, t, 8, 256);
    } else if (t < S0 + S1) {
        int u = t - S0;
        packB(W2l, g_bp1b, u, 16, 256);
        packB(W2r, g_bp2b, u, 16, 256);
    } else if (t < S0 + S1 + S2) {
        int u = t - S0 - S1;
        packB(W3l, g_bp1c, u, 16, 32);
        packB(W3r, g_bp2c, u, 16, 32);
    } else {
        int u = t - S0 - S1 - S2;
        if (u < N_NODES) cnt[u] = 0;
    }
}

// ==== fill CSR slots (blocks [0,FB)) + layer-1 dual GEMM (rest) ==========
#define FILL_BLOCKS ((E_TOT + 255) / 256)   // 1290
__global__ __launch_bounds__(256) void k_fill_gemm1(
    const int* __restrict__ ei,
    int* __restrict__ cnt, int* __restrict__ csr,
    const float4* __restrict__ A4,          // x, [N,128] f32
    const short8* __restrict__ Bp1, const short8* __restrict__ Bp2,
    unsigned short* __restrict__ C1b,       // xl out (bf16)
    float* __restrict__ C2)                 // xr out (f32)
{
    if (blockIdx.x < FILL_BLOCKS) {
        int e = blockIdx.x * 256 + threadIdx.x;
        if (e < E_TOT) {
            int src, dst;
            if (e < N_EDGES) { src = ei[e]; dst = ei[N_EDGES + e]; }
            else             { src = dst = e - N_EDGES; }
            int pos = atomicAdd(&cnt[dst], 1);
            if (pos < SLOTS) csr[dst * SLOTS + pos] = src;
        }
        return;
    }
    // ---- layer-1 dual GEMM: 32-row tiles, K=128 f32 inline split ----
    const int nkc = 8;                   // Kp = 256
    int mt   = blockIdx.x - FILL_BLOCKS;
    int lane = threadIdx.x & 63;
    int wid  = threadIdx.x >> 6;
    int quad = lane >> 4;
    int col  = lane & 15;
    int r0 = mt * 32 + col;       if (r0 >= N_NODES) r0 = N_NODES - 1;
    int r1 = mt * 32 + 16 + col;  if (r1 >= N_NODES) r1 = N_NODES - 1;
    const float4* a0 = A4 + (size_t)r0 * 32 + quad;   // K/4 = 32
    const float4* a1 = A4 + (size_t)r1 * 32 + quad;
    float4v acc[2][4][2];
    #pragma unroll
    for (int s = 0; s < 2; ++s)
        #pragma unroll
        for (int t = 0; t < 4; ++t) { acc[s][t][0] = (float4v)(0.f); acc[s][t][1] = (float4v)(0.f); }
    for (int kc = 0; kc < nkc; ++kc) {
        float4 v0 = a0[kc * 4];
        float4 v1 = a1[kc * 4];
        union { short8 s; unsigned int u[4]; } c0, c1;
        c0.u[0] = splitpack(v0.x); c0.u[1] = splitpack(v0.y);
        c0.u[2] = splitpack(v0.z); c0.u[3] = splitpack(v0.w);
        c1.u[0] = splitpack(v1.x); c1.u[1] = splitpack(v1.y);
        c1.u[2] = splitpack(v1.z); c1.u[3] = splitpack(v1.w);
        short8 A0 = c0.s, A1 = c1.s;
        #pragma unroll
        for (int t = 0; t < 4; ++t) {
            int nt = wid * 4 + t;
            size_t bi = ((size_t)(nt * nkc + kc)) * 64 + lane;
            short8 b1 = Bp1[bi];
            short8 b2 = Bp2[bi];
            acc[0][t][0] = __builtin_amdgcn_mfma_f32_16x16x32_bf16(A0, b1, acc[0][t][0], 0, 0, 0);
            acc[0][t][1] = __builtin_amdgcn_mfma_f32_16x16x32_bf16(A0, b2, acc[0][t][1], 0, 0, 0);
            acc[1][t][0] = __builtin_amdgcn_mfma_f32_16x16x32_bf16(A1, b1, acc[1][t][0], 0, 0, 0);
            acc[1][t][1] = __builtin_amdgcn_mfma_f32_16x16x32_bf16(A1, b2, acc[1][t][1], 0, 0, 0);
        }
    }
    #pragma unroll
    for (int s = 0; s < 2; ++s) {
        #pragma unroll
        for (int t = 0; t < 4; ++t) {
            int gc = (wid * 4 + t) * 16 + col;
            #pragma unroll
            for (int r = 0; r < 4; ++r) {
                int row = mt * 32 + s * 16 + quad * 4 + r;
                if (row < N_NODES) {
                    C1b[(size_t)row * 256 + gc] = f2bf(acc[s][t][0][r]);
                    C2[(size_t)row * 256 + gc]  = acc[s][t][1][r];
                }
            }
        }
    }
}

// ---------- MFMA split-bf16 dual GEMM (A pre-split): N=256 ---------------
__global__ __launch_bounds__(256) void k_mgemm2(const short8* __restrict__ Af,
                                                const short8* __restrict__ Bp1,
                                                const short8* __restrict__ Bp2,
                                                unsigned short* __restrict__ C1b,
                                                float* __restrict__ C2,
                                                int Kp, int nkc) {
    int mt   = blockIdx.x;
    int lane = threadIdx.x & 63;
    int wid  = threadIdx.x >> 6;
    int quad = lane >> 4;
    int col  = lane & 15;
    int ks   = Kp >> 3;
    int r0 = mt * 32 + col;       if (r0 >= N_NODES) r0 = N_NODES - 1;
    int r1 = mt * 32 + 16 + col;  if (r1 >= N_NODES) r1 = N_NODES - 1;
    const short8* a0 = Af + (size_t)r0 * ks + quad;
    const short8* a1 = Af + (size_t)r1 * ks + quad;
    float4v acc[2][4][2];
    #pragma unroll
    for (int s = 0; s < 2; ++s)
        #pragma unroll
        for (int t = 0; t < 4; ++t) { acc[s][t][0] = (float4v)(0.f); acc[s][t][1] = (float4v)(0.f); }
    for (int kc = 0; kc < nkc; ++kc) {
        short8 A0 = a0[kc * 4];
        short8 A1 = a1[kc * 4];
        #pragma unroll
        for (int t = 0; t < 4; ++t) {
            int nt = wid * 4 + t;
            size_t bi = ((size_t)(nt * nkc + kc)) * 64 + lane;
            short8 b1 = Bp1[bi];
            short8 b2 = Bp2[bi];
            acc[0][t][0] = __builtin_amdgcn_mfma_f32_16x16x32_bf16(A0, b1, acc[0][t][0], 0, 0, 0);
            acc[0][t][1] = __builtin_amdgcn_mfma_f32_16x16x32_bf16(A0, b2, acc[0][t][1], 0, 0, 0);
            acc[1][t][0] = __builtin_amdgcn_mfma_f32_16x16x32_bf16(A1, b1, acc[1][t][0], 0, 0, 0);
            acc[1][t][1] = __builtin_amdgcn_mfma_f32_16x16x32_bf16(A1, b2, acc[1][t][1], 0, 0, 0);
        }
    }
    #pragma unroll
    for (int s = 0; s < 2; ++s) {
        #pragma unroll
        for (int t = 0; t < 4; ++t) {
            int gc = (wid * 4 + t) * 16 + col;
            #pragma unroll
            for (int r = 0; r < 4; ++r) {
                int row = mt * 32 + s * 16 + quad * 4 + r;
                if (row < N_NODES) {
                    C1b[(size_t)row * 256 + gc] = f2bf(acc[s][t][0][r]);
                    C2[(size_t)row * 256 + gc]  = acc[s][t][1][r];
                }
            }
        }
    }
}

// ---------- MFMA dual GEMM, layer 3: N=32, Kp=512 (f32 outputs) ----------
__global__ __launch_bounds__(256) void k_mgemm32(const short8* __restrict__ Af,
                                                 const short8* __restrict__ Bp1,
                                                 const short8* __restrict__ Bp2,
                                                 float* __restrict__ C1,
                                                 float* __restrict__ C2) {
    int mt   = blockIdx.x;
    int lane = threadIdx.x & 63;
    int wid  = threadIdx.x >> 6;
    int quad = lane >> 4;
    int col  = lane & 15;
    int nt   = wid & 1;
    const short8* Bp = (wid < 2) ? Bp1 : Bp2;
    float* C = (wid < 2) ? C1 : C2;

    const short8* abase = Af + (size_t)(mt * 16 + col) * 64 + quad;  // Kp/8 = 64
    float4v acc = (float4v)(0.f);
    #pragma unroll 4
    for (int kc = 0; kc < 16; ++kc) {
        short8 a = abase[kc * 4];
        short8 b = Bp[((size_t)(nt * 16 + kc)) * 64 + lane];
        acc = __builtin_amdgcn_mfma_f32_16x16x32_bf16(a, b, acc, 0, 0, 0);
    }
    #pragma unroll
    for (int r = 0; r < 4; ++r)
        C[(size_t)(mt * 16 + quad * 4 + r) * 32 + nt * 16 + col] = acc[r];
}

// ------------- GATv2 attention + aggregation, heads=8, ch=32 -------------
// Block per node, 4 waves; wave covers full 256-ch row (float4/lane).
// Contiguous edge spans + one coalesced csr chunk-load per wave (span<=48),
// per-edge src via __shfl broadcast. leaky(t)=max(t,0.2t); att pre-scaled
// by log2e so softmax is raw exp2.
__global__ __launch_bounds__(256) void k_agg8(const unsigned short* __restrict__ xlb,
                                              const float4* __restrict__ xr4,
                                              const float4* __restrict__ att4,
                                              const float4* __restrict__ bias4,
                                              const int* __restrict__ cnt,
                                              const int* __restrict__ csr_src,
                                              const float4* __restrict__ res4,
                                              float4* __restrict__ out4,
                                              uint4* __restrict__ abf_out,
                                              int mode) {
    __shared__ float  ss[4][64];
    __shared__ float4 sacc[4][64];
    int node = blockIdx.x;
    int lane = threadIdx.x & 63;
    int wid  = threadIdx.x >> 6;
    float4 xrv = xr4[(size_t)node * 64 + lane];
    float4 av  = att4[lane];
    av.x *= LOG2E; av.y *= LOG2E; av.z *= LOG2E; av.w *= LOG2E;
    int c = cnt[node]; if (c > SLOTS) c = SLOTS;
    int start = node * SLOTS, end = start + c;
    int span = (c + 3) >> 2;             // contiguous edges per wave, <= 48
    int wbeg = start + wid * span;
    int wend = wbeg + span; if (wend > end) wend = end;
    int nloc = wend - wbeg;              // may be <= 0 for trailing waves

    int ldi = wbeg + lane;
    int idxv = csr_src[ldi < end ? ldi : (end - 1)];

    float s = 0.f;
    float4 acc = make_float4(0.f, 0.f, 0.f, 0.f);

    for (int j0 = 0; j0 < nloc; j0 += 4) {
        int srcs[4];
        ushort4 uv[4];
        #pragma unroll
        for (int j = 0; j < 4; ++j)
            srcs[j] = __shfl(idxv, j0 + j);
        #pragma unroll
        for (int j = 0; j < 4; ++j)
            uv[j] = *(const ushort4*)(xlb + (size_t)srcs[j] * 256 + 4 * lane);
        #pragma unroll
        for (int j = 0; j < 4; ++j) {
            if (j0 + j < nloc) {
                float4 xv;
                xv.x = bf2f(uv[j].x); xv.y = bf2f(uv[j].y);
                xv.z = bf2f(uv[j].z); xv.w = bf2f(uv[j].w);
                float tx = xv.x + xrv.x, ty = xv.y + xrv.y;
                float tz = xv.z + xrv.z, tw = xv.w + xrv.w;
                float w = fmaxf(tx, NEG_SLOPE * tx) * av.x
                        + fmaxf(ty, NEG_SLOPE * ty) * av.y
                        + fmaxf(tz, NEG_SLOPE * tz) * av.z
                        + fmaxf(tw, NEG_SLOPE * tw) * av.w;
                w += __shfl_xor(w, 1);
                w += __shfl_xor(w, 2);
                w += __shfl_xor(w, 4);
                float p = exp2f(w);
                s += p;
                acc.x += p * xv.x;
                acc.y += p * xv.y;
                acc.z += p * xv.z;
                acc.w += p * xv.w;
            }
        }
    }
    ss[wid][lane] = s;
    sacc[wid][lane] = acc;
    __syncthreads();
    if (wid == 0) {
        float S = ss[0][lane] + ss[1][lane] + ss[2][lane] + ss[3][lane];
        float4 A = make_float4(0.f, 0.f, 0.f, 0.f);
        #pragma unroll
        for (int w = 0; w < 4; ++w) {
            float4 a = sacc[w][lane];
            A.x += a.x; A.y += a.y; A.z += a.z; A.w += a.w;
        }
        float inv = 1.f / (S + 1e-16f);
        float4 bv = bias4[lane];
        float4 o;
        o.x = A.x * inv + bv.x; o.y = A.y * inv + bv.y;
        o.z = A.z * inv + bv.z; o.w = A.w * inv + bv.w;
        if (mode == 0) {
            o.x = fmaxf(o.x, 0.f); o.y = fmaxf(o.y, 0.f);
            o.z = fmaxf(o.z, 0.f); o.w = fmaxf(o.w, 0.f);
        } else {
            float4 r = res4[(size_t)node * 64 + lane];
            o.x += r.x; o.y += r.y; o.z += r.z; o.w += r.w;
        }
        if (out4) out4[(size_t)node * 64 + lane] = o;
        if (abf_out) {
            uint4 u;
            u.x = splitpack(o.x); u.y = splitpack(o.y);
            u.z = splitpack(o.z); u.w = splitpack(o.w);
            abf_out[(size_t)node * 64 + lane] = u;
        }
    }
}

// ------------- GATv2 attention + aggregation, heads=1, ch=32 -------------
__global__ __launch_bounds__(256) void k_agg1(const float4* __restrict__ xl4,
                                              const float4* __restrict__ xr4,
                                              const float4* __restrict__ att4,
                                              const float4* __restrict__ bias4,
                                              const int* __restrict__ cnt,
                                              const int* __restrict__ csr_src,
                                              float4* __restrict__ out4) {
    int node = blockIdx.x * 4 + (threadIdx.x >> 6);
    if (node >= N_NODES) return;
    int lane = threadIdx.x & 63;
    int q = lane & 7;
    int grp = lane >> 3;
    float4 xrv = xr4[(size_t)node * 8 + q];
    float4 av  = att4[q];
    av.x *= LOG2E; av.y *= LOG2E; av.z *= LOG2E; av.w *= LOG2E;
    int c = cnt[node]; if (c > SLOTS) c = SLOTS;
    int start = node * SLOTS, end = start + c;
    float s = 0.f;
    float4 acc = make_float4(0.f, 0.f, 0.f, 0.f);
    for (int i = start + grp; i < end; i += 8) {
        int src = csr_src[i];
        float4 xv = xl4[(size_t)src * 8 + q];
        float tx = xv.x + xrv.x, ty = xv.y + xrv.y;
        float tz = xv.z + xrv.z, tw = xv.w + xrv.w;
        float w = fmaxf(tx, NEG_SLOPE * tx) * av.x
                + fmaxf(ty, NEG_SLOPE * ty) * av.y
                + fmaxf(tz, NEG_SLOPE * tz) * av.z
                + fmaxf(tw, NEG_SLOPE * tw) * av.w;
        w += __shfl_xor(w, 1);
        w += __shfl_xor(w, 2);
        w += __shfl_xor(w, 4);
        float p = exp2f(w);
        s += p;
        acc.x += p * xv.x;
        acc.y += p * xv.y;
        acc.z += p * xv.z;
        acc.w += p * xv.w;
    }
    #pragma unroll
    for (int off = 8; off < 64; off <<= 1) {
        s     += __shfl_xor(s, off);
        acc.x += __shfl_xor(acc.x, off);
        acc.y += __shfl_xor(acc.y, off);
        acc.z += __shfl_xor(acc.z, off);
        acc.w += __shfl_xor(acc.w, off);
    }
    if (grp == 0) {
        float inv = 1.f / (s + 1e-16f);
        float4 bv = bias4[q];
        float4 o;
        o.x = acc.x * inv + bv.x; o.y = acc.y * inv + bv.y;
        o.z = acc.z * inv + bv.z; o.w = acc.w * inv + bv.w;
        out4[(size_t)node * 8 + q] = o;
    }
}

// -------------------------------- launch --------------------------------

extern "C" void kernel_launch(void* const* d_in, const int* in_sizes, int n_in,
                              void* d_out, int out_size, void* d_ws, size_t ws_size,
                              hipStream_t stream) {
    const float* x   = (const float*)d_in[0];
    const float* W1l = (const float*)d_in[1];
    const float* W1r = (const float*)d_in[2];
    const float* a1  = (const float*)d_in[3];
    const float* b1  = (const float*)d_in[4];
    const float* W2l = (const float*)d_in[5];
    const float* W2r = (const float*)d_in[6];
    const float* a2  = (const float*)d_in[7];
    const float* b2  = (const float*)d_in[8];
    const float* W3l = (const float*)d_in[9];
    const float* W3r = (const float*)d_in[10];
    const float* a3  = (const float*)d_in[11];
    const float* b3  = (const float*)d_in[12];
    const int*   ei  = (const int*)d_in[13];   // int32! harness converts int64 -> int32
    float* out = (float*)d_out;

    int *cnt, *csr;
    float *xl, *xr, *h1;
    unsigned short *xlb, *abf, *bp1a, *bp2a, *bp1b, *bp2b, *bp1c, *bp2c;
    hipGetSymbolAddress((void**)&cnt,    HIP_SYMBOL(g_cnt));
    hipGetSymbolAddress((void**)&csr,    HIP_SYMBOL(g_csr));
    hipGetSymbolAddress((void**)&xl,     HIP_SYMBOL(g_xl));
    hipGetSymbolAddress((void**)&xr,     HIP_SYMBOL(g_xr));
    hipGetSymbolAddress((void**)&h1,     HIP_SYMBOL(g_h1));
    hipGetSymbolAddress((void**)&xlb,    HIP_SYMBOL(g_xlb));
    hipGetSymbolAddress((void**)&abf,    HIP_SYMBOL(g_abf));
    hipGetSymbolAddress((void**)&bp1a,   HIP_SYMBOL(g_bp1a));
    hipGetSymbolAddress((void**)&bp2a,   HIP_SYMBOL(g_bp2a));
    hipGetSymbolAddress((void**)&bp1b,   HIP_SYMBOL(g_bp1b));
    hipGetSymbolAddress((void**)&bp2b,   HIP_SYMBOL(g_bp2b));
    hipGetSymbolAddress((void**)&bp1c,   HIP_SYMBOL(g_bp1c));
    hipGetSymbolAddress((void**)&bp2c,   HIP_SYMBOL(g_bp2c));

    // 1: pack 6 weight mats + zero slot counters
    k_prep<<<144, 256, 0, stream>>>(W1l, W1r, W2l, W2r, W3l, W3r, cnt);

    // 2: CSR slot-fill + layer-1 dual GEMM (independent roles, one launch)
    k_fill_gemm1<<<FILL_BLOCKS + (N_NODES + 31) / 32, 256, 0, stream>>>(
        ei, cnt, csr, (const float4*)x,
        (const short8*)bp1a, (const short8*)bp2a, xlb, xr);

    // 3: layer-1 aggregation (emits h1 f32 + abf split-bf16)
    k_agg8<<<N_NODES, 256, 0, stream>>>(xlb, (const float4*)xr,
                                        (const float4*)a1, (const float4*)b1,
                                        cnt, csr, nullptr, (float4*)h1,
                                        (uint4*)abf, 0);

    // 4: layer-2 dual GEMM (Kp=512 from abf)
    k_mgemm2<<<(N_NODES + 31) / 32, 256, 0, stream>>>((const short8*)abf,
                                                      (const short8*)bp1b, (const short8*)bp2b,
                                                      xlb, xr, 512, 16);

    // 5: layer-2 aggregation (+ residual; emits abf for L3)
    k_agg8<<<N_NODES, 256, 0, stream>>>(xlb, (const float4*)xr,
                                        (const float4*)a2, (const float4*)b2,
                                        cnt, csr, (const float4*)h1, nullptr,
                                        (uint4*)abf, 1);

    // 6: layer-3 dual GEMM (N=32)
    k_mgemm32<<<N_NODES / 16, 256, 0, stream>>>((const short8*)abf,
                                                (const short8*)bp1c, (const short8*)bp2c,
                                                xl, xr);

    // 7: heads=1 aggregation -> output
    k_agg1<<<(N_NODES + 3) / 4, 256, 0, stream>>>((const float4*)xl, (const float4*)xr,
                                                  (const float4*)a3, (const float4*)b3,
                                                  cnt, csr, (float4*)out);
}